// Round 11
// baseline (1630.403 us; speedup 1.0000x reference)
//
#include <hip/hip_runtime.h>
#include <math.h>

#define LAYERS 12
#define EE 1024
#define GG 2730
#define VV 16416
#define EPS 1e-6f
#define NBLK 512
#define NGRP 32
#define GRPSZ (NBLK/NGRP)

// ---- workspace layout (float offsets) ----
#define OFF_DS 0
#define NSLOT 37
#define OFF_ACC (OFF_DS + NSLOT*2048)
#define ACC_STRIDE 28672
#define AQ 0
#define AK 2048
#define AV 4096
#define AY 6144
#define ASC 10240
#define AOUT 12288
#define AY2 14336
#define AA 16384
#define AB2 21844
#define ACC_TOTAL (LAYERS*ACC_STRIDE)
#define OFF_BAR (OFF_ACC + ACC_TOTAL)
#define ZERO_FLOATS (NSLOT*2048 + ACC_TOTAL + 8192)

#define KVL 524288
#define KVB 262144

struct MegaP {
  const float* enc; const float* keys_in; const float* values_in;
  const int* maski; const int* pt; const int* ti;
  const float* tok; const float* pos; const float* ln_s; const float* ln_b;
  const float* final_b; const float* lm_w;
  const float* pre_sa_b; const float* saq; const float* sak; const float* sav;
  const float* sao; const float* sas; const float* sab;
  const float* pre_ca_b; const float* caq; const float* ckw; const float* cvw;
  const float* cao; const float* cas; const float* cab;
  const float* g0b; const float* f0; const float* f1; const float* g1b; const float* f2;
  float* logits; float* keys_out; float* values_out; float* ws;
};

// device-coherent (cache-bypassing) load for inter-stage data
__device__ __forceinline__ float gload(const float* p){
  return __hip_atomic_load(p, __ATOMIC_RELAXED, __HIP_MEMORY_SCOPE_AGENT);
}

// fence-free tree barrier: relaxed atomics only; data flows via device-scope
// atomics (writes) + gload (reads), so no L2 writeback/invalidate is needed.
__device__ __forceinline__ void bar_sync(int* bar, int gen){
  asm volatile("s_waitcnt vmcnt(0)" ::: "memory");
  __syncthreads();
  if (threadIdx.x==0){
    int grp = blockIdx.x & (NGRP-1);
    int v = __hip_atomic_fetch_add(&bar[grp*64], 1, __ATOMIC_RELAXED, __HIP_MEMORY_SCOPE_AGENT);
    if (v == gen*GRPSZ + (GRPSZ-1)){
      int m = __hip_atomic_fetch_add(&bar[2048], 1, __ATOMIC_RELAXED, __HIP_MEMORY_SCOPE_AGENT);
      if (m == gen*NGRP + (NGRP-1)){
        #pragma unroll 4
        for (int q=0;q<NGRP;q++)
          __hip_atomic_store(&bar[2112+q*64], gen+1, __ATOMIC_RELAXED, __HIP_MEMORY_SCOPE_AGENT);
      }
    }
    int it=0;
    while (__hip_atomic_load(&bar[2112+grp*64], __ATOMIC_RELAXED, __HIP_MEMORY_SCOPE_AGENT) <= gen){
      __builtin_amdgcn_s_sleep(8);
      if (++it > (1<<14)) break;   // valve: fail absmax, don't hang
    }
  }
  __syncthreads();
  asm volatile("" ::: "memory");
}

__device__ __forceinline__ void red4(float* sm, float& a, float& b, float& c, float& d){
  #pragma unroll
  for(int o=32;o;o>>=1){ a+=__shfl_down(a,o); b+=__shfl_down(b,o); c+=__shfl_down(c,o); d+=__shfl_down(d,o); }
  int w=threadIdx.x>>6, l=threadIdx.x&63;
  __syncthreads();
  if(l==0){ sm[w]=a; sm[4+w]=b; sm[8+w]=c; sm[12+w]=d; }
  __syncthreads();
  a=sm[0]+sm[1]+sm[2]+sm[3]; b=sm[4]+sm[5]+sm[6]+sm[7];
  c=sm[8]+sm[9]+sm[10]+sm[11]; d=sm[12]+sm[13]+sm[14]+sm[15];
}

__device__ __forceinline__ void ln_stats_gl(const float* v, int K, float* sm,
    float& mu0, float& rs0, float& mu1, float& rs1){
  float s0=0,q0=0,s1=0,q1=0;
  for(int i=threadIdx.x;i<K;i+=256){ float a=gload(v+i), b=gload(v+K+i); s0+=a;q0+=a*a;s1+=b;q1+=b*b; }
  red4(sm,s0,q0,s1,q1);
  mu0=s0/K; mu1=s1/K;
  rs0=rsqrtf(fmaxf(q0/K-mu0*mu0,0.f)+EPS);
  rs1=rsqrtf(fmaxf(q1/K-mu1*mu1,0.f)+EPS);
}

__device__ __forceinline__ void ln_stats_l(float (*Ds)[1024], float* sm,
    float& mu0, float& rs0, float& mu1, float& rs1){
  float s0=0,q0=0,s1=0,q1=0;
  for(int i=threadIdx.x;i<EE;i+=256){ float a=Ds[0][i], b=Ds[1][i]; s0+=a;q0+=a*a;s1+=b;q1+=b*b; }
  red4(sm,s0,q0,s1,q1);
  mu0=s0/EE; mu1=s1/EE;
  rs0=rsqrtf(fmaxf(q0/EE-mu0*mu0,0.f)+EPS);
  rs1=rsqrtf(fmaxf(q1/EE-mu1*mu1,0.f)+EPS);
}

__device__ __forceinline__ void build_ds3_gl(const float* dsi, const float* accL,
    const float* sasl, const float* sabl, const float* casl, const float* cabl,
    float (*Ds)[1024], float* sm){
  float mu0,rs0,mu1,rs1;
  ln_stats_gl(accL+AY, EE, sm, mu0,rs0,mu1,rs1);
  for(int i=threadIdx.x;i<EE;i+=256){ float sc=sasl[i], bi=sabl[i];
    Ds[0][i]=gload(dsi+i)    + (gload(accL+AY+i)-mu0)*rs0*sc + bi;
    Ds[1][i]=gload(dsi+EE+i) + (gload(accL+AY+EE+i)-mu1)*rs1*sc + bi; }
  ln_stats_gl(accL+AY2, EE, sm, mu0,rs0,mu1,rs1);
  for(int i=threadIdx.x;i<EE;i+=256){ float sc=casl[i], bi=cabl[i];
    Ds[0][i] += (gload(accL+AY2+i)-mu0)*rs0*sc + bi;
    Ds[1][i] += (gload(accL+AY2+EE+i)-mu1)*rs1*sc + bi; }
}

__global__ __launch_bounds__(256, 2)
void k_mega(MegaP p){
  __shared__ float LB[7536];
  const int t = threadIdx.x;
  const int bkid = blockIdx.x;
  int* bar = (int*)(p.ws + OFF_BAR);
  const int tiv = p.ti[0];
  int g = 0;

  // ===== stage P: prelude (block 0) + full KV-cache copy (blocks 1..511, skip row tiv)
  if (bkid==0){
    float* ev = LB; float* sm = LB+1024;
    int ptv = p.pt[0];
    float s0=0,q0=0,d1=0,d2=0;
    for(int i=t;i<EE;i+=256){ float v=p.tok[(size_t)ptv*EE+i]+p.pos[(size_t)tiv*EE+i]; ev[i]=v; s0+=v; q0+=v*v; }
    red4(sm,s0,q0,d1,d2);
    float mu=s0/EE, rs=rsqrtf(fmaxf(q0/EE-mu*mu,0.f)+EPS);
    float* ds0 = p.ws + OFF_DS;
    __syncthreads();
    for(int i=t;i<EE;i+=256){ float y=(ev[i]-mu)*rs*p.ln_s[i]+p.ln_b[i]; atomicAdd(&ds0[i],y); atomicAdd(&ds0[EE+i],y); }
  } else {
    for (int i=(bkid-1)*256+t; i<3145728; i+=511*256){
      int kv = (i>=1572864);
      int r = i - (kv?1572864:0);
      int ll=r>>17, r2=r&131071, bb=r2>>16, r3=r2&65535, tt=r3>>8, e4=r3&255;
      if (tt==tiv) continue;
      size_t off=(size_t)ll*KVL+(size_t)bb*KVB+(size_t)tt*EE+(size_t)e4*4;
      float4 v=*(const float4*)((kv?p.values_in:p.keys_in)+off);
      *(float4*)((kv?p.values_out:p.keys_out)+off)=v;
    }
  }
  bar_sync(bar, g++);

  for (int l=0;l<LAYERS;l++){
    float* accL = p.ws + OFF_ACC + (size_t)l*ACC_STRIDE;
    const float* dsi = p.ws + OFF_DS + (size_t)(3*l)*2048;
    float* ds4 = p.ws + OFF_DS + (size_t)(3*l+3)*2048;
    const size_t lE2=(size_t)l*EE*EE, lE=(size_t)l*EE;
    const size_t lEG=(size_t)l*EE*GG, lGE=(size_t)l*GG*EE, lG=(size_t)l*GG;

    // ===== stage A: x=LN(dsi)+pre_sa_b ; q,k,v GEMV. 492 blocks, CH=25, depth 41.
    if (bkid < 492){
      float* Xs0=LB; float* Xs1=LB+1024; float* sm=LB+2048;
      int cg=bkid%12, ks=bkid/12;
      int c=cg*256+t, sel=c>>10, cc=c&1023;
      const float* W = (sel==0? p.saq : sel==1? p.sak : p.sav) + lE2;
      float* O = accL + (sel==0? AQ : sel==1? AK : AV);
      int k0=ks*25;
      const float* wp = W + (size_t)k0*EE + cc;
      float wr[25];
      #pragma unroll
      for(int k=0;k<25;k++) wr[k] = (k0+k<EE)? wp[(size_t)k*EE] : 0.f;
      float mu0,rs0,mu1,rs1;
      ln_stats_gl(dsi, EE, sm, mu0,rs0,mu1,rs1);
      for(int i=t;i<EE;i+=256){ float bi=p.pre_sa_b[lE+i];
        Xs0[i]=(gload(dsi+i)-mu0)*rs0+bi; Xs1[i]=(gload(dsi+EE+i)-mu1)*rs1+bi; }
      __syncthreads();
      float a0=0,a1=0;
      #pragma unroll
      for(int k=0;k<25;k++){ if(k0+k<EE){ a0+=Xs0[k0+k]*wr[k]; a1+=Xs1[k0+k]*wr[k]; } }
      atomicAdd(&O[cc],a0); atomicAdd(&O[EE+cc],a1);
    }
    bar_sync(bar, g++);

    // ===== stage B: self-attention + y = attn@sao. 256 blocks. Writes new KV row.
    if (bkid < 256){
      float (*Ds)[1024] = (float(*)[1024])LB;
      float (*att)[256] = (float(*)[256])(LB+2048);
      float* sm = LB+2560;
      int cg=bkid&3, h=(bkid>>2)&15, sub=(bkid>>6)&3, hoff=h*64;
      if (t < 128){ int bb2=t>>6, c2=t&63; Ds[bb2][c2] = gload(accL+AQ+bb2*EE+hoff+c2)*0.125f; }
      __syncthreads();
      for(int bb2=0;bb2<2;bb2++)
        for(int tt=t; tt<=tiv; tt+=256){
          float d=0;
          if (tt<tiv){
            const float* kr = p.keys_in + (size_t)l*KVL + (size_t)bb2*KVB + (size_t)tt*EE + hoff;
            #pragma unroll
            for(int c2=0;c2<64;c2++) d += Ds[bb2][c2]*kr[c2];
          } else {
            const float* kr = accL + AK + bb2*EE + hoff;
            #pragma unroll
            for(int c2=0;c2<64;c2++) d += Ds[bb2][c2]*gload(kr+c2);
          }
          att[bb2][tt] = d;
        }
      __syncthreads();
      int wv=t>>6, l2=t&63;
      if (wv<2){
        float m=-3.4e38f;
        for(int tt=l2; tt<=tiv; tt+=64) m=fmaxf(m, att[wv][tt]);
        #pragma unroll
        for(int o=32;o;o>>=1) m=fmaxf(m,__shfl_xor(m,o));
        float s=0;
        for(int tt=l2; tt<=tiv; tt+=64){ float e=__expf(att[wv][tt]-m); att[wv][tt]=e; s+=e; }
        #pragma unroll
        for(int o=32;o;o>>=1) s+=__shfl_xor(s,o);
        if(l2==0) sm[8+wv]=1.f/s;
      }
      __syncthreads();
      {
        int bb2=t>>7, j=(t>>3)&15, part=t&7, colh=sub*16+j;
        float v=0;
        for(int tt=part; tt<=tiv; tt+=8){
          float vv = (tt<tiv)? p.values_in[(size_t)l*KVL + (size_t)bb2*KVB + (size_t)tt*EE + hoff + colh]
                             : gload(accL+AV+bb2*EE+hoff+colh);
          v += att[bb2][tt]*vv;
        }
        v += __shfl_down(v,4,8); v += __shfl_down(v,2,8); v += __shfl_down(v,1,8);
        if(part==0) Ds[bb2][512+j] = v*sm[8+bb2];
      }
      __syncthreads();
      {
        int c = cg*256+t, kb = hoff + sub*16;
        const float* wp = p.sao + lE2 + (size_t)kb*EE + c;
        float a0=0,a1=0;
        #pragma unroll
        for(int j2=0;j2<16;j2++){ float w=wp[(size_t)j2*EE]; a0+=Ds[0][512+j2]*w; a1+=Ds[1][512+j2]*w; }
        atomicAdd(&accL[AY+c],a0); atomicAdd(&accL[AY+EE+c],a1);
      }
      if (cg==0 && sub==0){
        int bb2=t>>7, kv=(t>>6)&1, c2=t&63;
        float val = gload(accL + (kv?AV:AK) + bb2*EE + hoff + c2);
        float* dst = (kv? p.values_out : p.keys_out)
                   + (size_t)l*KVL + (size_t)bb2*KVB + (size_t)tiv*EE + hoff + c2;
        *dst = val;
      }
    }
    bar_sync(bar, g++);

    // ===== stage C: ds2->x2, qc_h, u, partial scores. 128 blocks (bh*4+ec).
    if (bkid < 128){
      float* Xs = LB; float* Pq = LB+1024; float* qs = LB+2048;
      float* us = LB+2112; float* sm = LB+2368;
      int bh=bkid>>2, ec=bkid&3;
      int b=bh>>4, h=bh&15, hoff=h*64;
      const int w=t>>6, ln=t&63;
      float s0=0,q0=0;
      for(int i=t;i<EE;i+=256){ float v=gload(accL+AY+b*EE+i); s0+=v; q0+=v*v; }
      #pragma unroll
      for(int o=32;o;o>>=1){ s0+=__shfl_down(s0,o); q0+=__shfl_down(q0,o); }
      if(ln==0){ sm[w]=s0; sm[4+w]=q0; }
      __syncthreads();
      float mu=(sm[0]+sm[1]+sm[2]+sm[3])/EE;
      float qq=(sm[4]+sm[5]+sm[6]+sm[7])/EE;
      float rs=rsqrtf(fmaxf(qq-mu*mu,0.f)+EPS);
      float s1=0,q1=0;
      for(int i=t;i<EE;i+=256){
        float d = gload(dsi+b*EE+i) + (gload(accL+AY+b*EE+i)-mu)*rs*p.sas[lE+i] + p.sab[lE+i];
        Xs[i]=d; s1+=d; q1+=d*d;
      }
      #pragma unroll
      for(int o=32;o;o>>=1){ s1+=__shfl_down(s1,o); q1+=__shfl_down(q1,o); }
      if(ln==0){ sm[8+w]=s1; sm[12+w]=q1; }
      __syncthreads();
      float mu2=(sm[8]+sm[9]+sm[10]+sm[11])/EE;
      float q2=(sm[12]+sm[13]+sm[14]+sm[15])/EE;
      float rs2=rsqrtf(fmaxf(q2-mu2*mu2,0.f)+EPS);
      for(int i=t;i<EE;i+=256) Xs[i] = (Xs[i]-mu2)*rs2 + p.pre_ca_b[lE+i];
      __syncthreads();
      {
        int c4=t&15, kr=t>>4;
        const float4* cq = (const float4*)(p.caq + lE2 + (size_t)kr*EE + hoff) + c4;
        float ax=0,ay=0,az=0,aw=0;
        #pragma unroll 8
        for(int i=0;i<64;i++){
          float4 wv = cq[(size_t)i*16*256];
          float x = Xs[kr+16*i];
          ax+=x*wv.x; ay+=x*wv.y; az+=x*wv.z; aw+=x*wv.w;
        }
        Pq[kr*64+c4*4+0]=ax; Pq[kr*64+c4*4+1]=ay; Pq[kr*64+c4*4+2]=az; Pq[kr*64+c4*4+3]=aw;
      }
      __syncthreads();
      if (t<64){
        float qv=0;
        #pragma unroll
        for(int kr=0;kr<16;kr++) qv += Pq[kr*64+t];
        qs[t] = qv*0.125f;
      }
      __syncthreads();
      {
        const float4* ckp = (const float4*)(p.ckw + lE2 + (size_t)(ec*256+t)*EE + hoff);
        float u=0;
        #pragma unroll
        for(int j=0;j<16;j++){
          float4 wv=ckp[j];
          u += wv.x*qs[4*j] + wv.y*qs[4*j+1] + wv.z*qs[4*j+2] + wv.w*qs[4*j+3];
        }
        us[t]=u;
      }
      __syncthreads();
      int t2=t&63, q4=t>>6;
      const float4* ep = (const float4*)(p.enc + (size_t)(b*64+t2)*EE + ec*256 + q4*64);
      float pa=0;
      #pragma unroll
      for(int j=0;j<16;j++){
        float4 e4=ep[j];
        pa += e4.x*us[q4*64+4*j] + e4.y*us[q4*64+4*j+1] + e4.z*us[q4*64+4*j+2] + e4.w*us[q4*64+4*j+3];
      }
      atomicAdd(&accL[ASC + (b*16+h)*64 + t2], pa);
    }
    bar_sync(bar, g++);

    // ===== stage D: softmax + ctx + out = ctx@cvw. 256 blocks (bh*8+es).
    if (bkid < 256){
      float* att = LB; float* ctxp = LB+64; float* ctxs = LB+320; float* smr = LB+448;
      int bh=bkid>>3, es=bkid&7;
      int b=bh>>4, h=bh&15, hoff=h*64, e0=es*128;
      const int c=t&63, part=t>>6;
      const float* vp = p.cvw + lE2 + (size_t)(e0+part*32)*EE + hoff + c;
      float wr[32];
      #pragma unroll
      for(int j=0;j<32;j++) wr[j] = vp[(size_t)j*EE];
      if (t<64){
        float sc = gload(accL + ASC + (b*16+h)*64 + t);
        int mi=b*64+t;
        bool valid = (p.maski[mi]!=0) || (((const unsigned char*)p.maski)[mi]!=0);
        sc = valid? sc : -3.4e38f;
        float m=sc;
        #pragma unroll
        for(int o=32;o;o>>=1) m=fmaxf(m,__shfl_xor(m,o));
        float e_ = valid? __expf(sc-m) : 0.f;
        float s=e_;
        #pragma unroll
        for(int o=32;o;o>>=1) s+=__shfl_xor(s,o);
        att[t]=e_;
        if(t==0) smr[0]=1.f/s;
      }
      __syncthreads();
      {
        int e2=t>>1, half=t&1;
        const float* ep = p.enc + (size_t)(b*64+half*32)*EE + e0+e2;
        float ca=0;
        #pragma unroll 8
        for(int tt=0;tt<32;tt++) ca += att[half*32+tt]*ep[(size_t)tt*EE];
        ctxp[half*128+e2]=ca;
      }
      __syncthreads();
      if (t<128) ctxs[t] = (ctxp[t]+ctxp[128+t])*smr[0];
      __syncthreads();
      float a=0;
      #pragma unroll
      for(int j=0;j<32;j++) a += ctxs[part*32+j]*wr[j];
      atomicAdd(&accL[AOUT + b*EE + hoff + c], a);
    }
    bar_sync(bar, g++);

    // ===== stage E: y2 = out @ cao. 256 blocks, CH=16, depth 64.
    if (bkid < 256){
      float* Xs0=LB; float* Xs1=LB+1024;
      int cg=bkid&3, ks=bkid>>2;
      int c = cg*256 + t;
      int k0 = ks*16;
      const float* wp = p.cao + lE2 + (size_t)k0*EE + c;
      float wr[16];
      #pragma unroll
      for(int k=0;k<16;k++) wr[k] = wp[(size_t)k*EE];
      for(int i=t;i<EE;i+=256){ Xs0[i]=gload(accL+AOUT+i); Xs1[i]=gload(accL+AOUT+EE+i); }
      __syncthreads();
      float a0=0,a1=0;
      #pragma unroll
      for(int k=0;k<16;k++){ a0+=Xs0[k0+k]*wr[k]; a1+=Xs1[k0+k]*wr[k]; }
      atomicAdd(&accL[AY2+c],a0); atomicAdd(&accL[AY2+EE+c],a1);
    }
    bar_sync(bar, g++);

    // ===== stage F: ds3 ; z=LN(ds3)+g0b ; a=z@f0, b=z@f1. 495 blocks, CH=23, depth 45.
    if (bkid < 495){
      float* Xs0=LB; float* Xs1=LB+1024;
      float (*Ds)[1024]=(float(*)[1024])(LB+2048);
      float* sm=LB+4096;
      int cg=bkid%11, ks=bkid/11;
      int c2 = cg*256 + t;
      int k0 = ks*23;
      int sel=0, col=0;
      float2 wr[23];
      if (c2 < 2730){
        sel = (c2>=1365); int cc2 = sel? c2-1365 : c2; col = cc2*2;
        const float* W = (sel? p.f1 : p.f0) + lEG;
        const float2* wp = (const float2*)(W + (size_t)k0*GG + col);
        #pragma unroll
        for(int k=0;k<23;k++) wr[k] = (k0+k<EE)? wp[(size_t)k*1365] : make_float2(0.f,0.f);
      }
      build_ds3_gl(dsi, accL, p.sas+lE, p.sab+lE, p.cas+lE, p.cab+lE, Ds, sm);
      float mu0,rs0,mu1,rs1;
      ln_stats_l(Ds, sm, mu0,rs0,mu1,rs1);
      for(int i=t;i<EE;i+=256){ float bi=p.g0b[lE+i];
        Xs0[i]=(Ds[0][i]-mu0)*rs0+bi; Xs1[i]=(Ds[1][i]-mu1)*rs1+bi; }
      __syncthreads();
      if (c2 < 2730){
        float* O = accL + (sel? AB2 : AA);
        float a0=0,a1=0,b0=0,b1=0;
        #pragma unroll
        for(int k=0;k<23;k++){
          if (k0+k<EE){
            float x0=Xs0[k0+k], x1=Xs1[k0+k];
            a0+=x0*wr[k].x; a1+=x0*wr[k].y; b0+=x1*wr[k].x; b1+=x1*wr[k].y;
          }
        }
        atomicAdd(&O[col+0],a0); atomicAdd(&O[col+1],a1);
        atomicAdd(&O[GG+col+0],b0); atomicAdd(&O[GG+col+1],b1);
      }
    }
    bar_sync(bar, g++);

    // ===== stage G: t=gelu(a)*b ; z2=LN(t)+g1b ; ds4 = ds3 + z2@f2. 256 blocks, CH=43, depth 64.
    if (bkid < 256){
      float* Xs0=LB; float* Xs1=LB+2736;
      float (*Ds)[1024]=(float(*)[1024])(LB+5472);
      float* sm=LB+7520;
      int cg=bkid&3, ks=bkid>>2;
      int c = cg*256 + t;
      int k0 = ks*43;
      const float* wp = p.f2 + lGE + (size_t)k0*EE + c;
      float wr[43];
      #pragma unroll
      for(int k=0;k<43;k++) wr[k] = (k0+k<GG)? wp[(size_t)k*EE] : 0.f;
      if (ks==0) build_ds3_gl(dsi, accL, p.sas+lE, p.sab+lE, p.cas+lE, p.cab+lE, Ds, sm);
      float s0=0,q0=0,s1=0,q1=0;
      for(int i=t;i<GG;i+=256){
        float a0v=gload(accL+AA+i), a1v=gload(accL+AA+GG+i);
        float b0v=gload(accL+AB2+i), b1v=gload(accL+AB2+GG+i);
        float g0v=0.5f*a0v*(1.f+erff(a0v*0.70710678118654752f));
        float g1v=0.5f*a1v*(1.f+erff(a1v*0.70710678118654752f));
        float t0=g0v*b0v, t1=g1v*b1v;
        Xs0[i]=t0; Xs1[i]=t1;
        s0+=t0;q0+=t0*t0;s1+=t1;q1+=t1*t1;
      }
      red4(sm,s0,q0,s1,q1);
      float mu0=s0/GG, mu1=s1/GG;
      float rs0=rsqrtf(fmaxf(q0/GG-mu0*mu0,0.f)+EPS), rs1=rsqrtf(fmaxf(q1/GG-mu1*mu1,0.f)+EPS);
      for(int i=t;i<GG;i+=256){ float bi=p.g1b[lG+i];
        Xs0[i]=(Xs0[i]-mu0)*rs0+bi; Xs1[i]=(Xs1[i]-mu1)*rs1+bi; }
      __syncthreads();
      float a0=0,b0=0;
      if (ks==0){ a0=Ds[0][c]; b0=Ds[1][c]; }
      #pragma unroll
      for(int k=0;k<43;k++){
        if (k0+k<GG){ a0+=Xs0[k0+k]*wr[k]; b0+=Xs1[k0+k]*wr[k]; }
      }
      atomicAdd(&ds4[c],a0); atomicAdd(&ds4[EE+c],b0);
    }
    bar_sync(bar, g++);
  }

  // ===== final: logits = LN(ds,final_b) @ lm_head. 510 blocks, CH=35, depth 30.
  if (bkid < 510){
    float* Xs0=LB; float* Xs1=LB+1024; float* sm=LB+2048;
    const float* dsf = p.ws + OFF_DS + (size_t)36*2048;
    int cg=bkid%17, ks=bkid/17;
    int c4 = cg*256 + t;
    int k0 = ks*35;
    float mu0,rs0,mu1,rs1;
    ln_stats_gl(dsf, EE, sm, mu0,rs0,mu1,rs1);
    for(int i=t;i<EE;i+=256){ float bi=p.final_b[i];
      Xs0[i]=(gload(dsf+i)-mu0)*rs0+bi; Xs1[i]=(gload(dsf+EE+i)-mu1)*rs1+bi; }
    __syncthreads();
    if (c4 < 4104){
      int col = c4*4;
      const float4* wp = (const float4*)(p.lm_w + (size_t)k0*VV + col);
      float a0=0,a1=0,a2=0,a3=0,b0=0,b1=0,b2=0,b3=0;
      #pragma unroll 5
      for(int k=0;k<35;k++){
        if (k0+k<EE){
          float4 w=wp[(size_t)k*4104];
          float x0=Xs0[k0+k], x1=Xs1[k0+k];
          a0+=x0*w.x; a1+=x0*w.y; a2+=x0*w.z; a3+=x0*w.w;
          b0+=x1*w.x; b1+=x1*w.y; b2+=x1*w.z; b3+=x1*w.w;
        }
      }
      atomicAdd(&p.logits[col+0],a0); atomicAdd(&p.logits[col+1],a1);
      atomicAdd(&p.logits[col+2],a2); atomicAdd(&p.logits[col+3],a3);
      atomicAdd(&p.logits[VV+col+0],b0); atomicAdd(&p.logits[VV+col+1],b1);
      atomicAdd(&p.logits[VV+col+2],b2); atomicAdd(&p.logits[VV+col+3],b3);
    }
  }
}

extern "C" void kernel_launch(void* const* d_in, const int* in_sizes, int n_in,
                              void* d_out, int out_size, void* d_ws, size_t ws_size,
                              hipStream_t stream){
  (void)in_sizes; (void)n_in; (void)out_size; (void)ws_size;
  float* out = (float*)d_out;
  float* ws = (float*)d_ws;

  MegaP P;
  P.enc        = (const float*)d_in[0];
  P.keys_in    = (const float*)d_in[1];
  P.values_in  = (const float*)d_in[2];
  P.maski      = (const int*)d_in[3];
  P.pt         = (const int*)d_in[4];
  P.ti         = (const int*)d_in[5];
  P.tok        = (const float*)d_in[6];
  P.pos        = (const float*)d_in[7];
  P.ln_s       = (const float*)d_in[8];
  P.ln_b       = (const float*)d_in[9];
  P.final_b    = (const float*)d_in[10];
  P.lm_w       = (const float*)d_in[11];
  P.pre_sa_b   = (const float*)d_in[12];
  P.saq        = (const float*)d_in[13];
  P.sak        = (const float*)d_in[14];
  P.sav        = (const float*)d_in[15];
  P.sao        = (const float*)d_in[16];
  P.sas        = (const float*)d_in[17];
  P.sab        = (const float*)d_in[18];
  P.pre_ca_b   = (const float*)d_in[19];
  P.caq        = (const float*)d_in[20];
  P.ckw        = (const float*)d_in[21];
  P.cvw        = (const float*)d_in[22];
  P.cao        = (const float*)d_in[23];
  P.cas        = (const float*)d_in[24];
  P.cab        = (const float*)d_in[25];
  P.g0b        = (const float*)d_in[26];
  P.f0         = (const float*)d_in[27];
  P.f1         = (const float*)d_in[28];
  P.g1b        = (const float*)d_in[29];
  P.f2         = (const float*)d_in[30];
  P.logits     = out;
  P.keys_out   = out + (size_t)2*VV;
  P.values_out = P.keys_out + (size_t)LAYERS*KVL;
  P.ws         = ws;

  hipMemsetAsync(ws + OFF_DS, 0, (size_t)ZERO_FLOATS*sizeof(float), stream);
  hipMemsetAsync(P.logits, 0, (size_t)2*VV*sizeof(float), stream);

  k_mega<<<NBLK,256,0,stream>>>(P);
}

// Round 12
// 1237.067 us; speedup vs baseline: 1.3180x; 1.3180x over previous
//
#include <hip/hip_runtime.h>
#include <math.h>

#define LAYERS 12
#define EE 1024
#define GG 2730
#define VV 16416
#define EPS 1e-6f

// ---- workspace layout (float offsets) ----
#define OFF_DS 0
#define NSLOT 37
#define OFF_ACC (OFF_DS + NSLOT*2048)
#define ACC_STRIDE 28672
#define AQ 0
#define AK 2048
#define AV 4096
#define AY 6144
#define ASC 10240
#define AY2 14336
#define AA 16384
#define AB2 21844
#define ACC_TOTAL (LAYERS*ACC_STRIDE)

#define KVL 524288   // floats per layer per cache (2 batches x 256 x 1024)
#define KVB 262144   // floats per batch

struct MegaP {
  const float* enc; const float* keys_in; const float* values_in;
  const int* maski; const int* pt; const int* ti;
  const float* tok; const float* pos; const float* ln_s; const float* ln_b;
  const float* final_b; const float* lm_w;
  const float* pre_sa_b; const float* saq; const float* sak; const float* sav;
  const float* sao; const float* sas; const float* sab;
  const float* pre_ca_b; const float* caq; const float* ckw; const float* cvw;
  const float* cao; const float* cas; const float* cab;
  const float* g0b; const float* f0; const float* f1; const float* g1b; const float* f2;
  float* logits; float* keys_out; float* values_out; float* ws;
};

__device__ __forceinline__ void red4(float* sm, float& a, float& b, float& c, float& d){
  #pragma unroll
  for(int o=32;o;o>>=1){ a+=__shfl_down(a,o); b+=__shfl_down(b,o); c+=__shfl_down(c,o); d+=__shfl_down(d,o); }
  int w=threadIdx.x>>6, l=threadIdx.x&63;
  __syncthreads();
  if(l==0){ sm[w]=a; sm[4+w]=b; sm[8+w]=c; sm[12+w]=d; }
  __syncthreads();
  a=sm[0]+sm[1]+sm[2]+sm[3]; b=sm[4]+sm[5]+sm[6]+sm[7];
  c=sm[8]+sm[9]+sm[10]+sm[11]; d=sm[12]+sm[13]+sm[14]+sm[15];
}

__device__ __forceinline__ void ln_stats_g(const float* v, int K, float* sm,
    float& mu0, float& rs0, float& mu1, float& rs1){
  float s0=0,q0=0,s1=0,q1=0;
  for(int i=threadIdx.x;i<K;i+=256){ float a=v[i], b=v[K+i]; s0+=a;q0+=a*a;s1+=b;q1+=b*b; }
  red4(sm,s0,q0,s1,q1);
  mu0=s0/K; mu1=s1/K;
  rs0=rsqrtf(fmaxf(q0/K-mu0*mu0,0.f)+EPS);
  rs1=rsqrtf(fmaxf(q1/K-mu1*mu1,0.f)+EPS);
}

__device__ __forceinline__ void ln_stats_l(float (*Ds)[1024], float* sm,
    float& mu0, float& rs0, float& mu1, float& rs1){
  float s0=0,q0=0,s1=0,q1=0;
  for(int i=threadIdx.x;i<EE;i+=256){ float a=Ds[0][i], b=Ds[1][i]; s0+=a;q0+=a*a;s1+=b;q1+=b*b; }
  red4(sm,s0,q0,s1,q1);
  mu0=s0/EE; mu1=s1/EE;
  rs0=rsqrtf(fmaxf(q0/EE-mu0*mu0,0.f)+EPS);
  rs1=rsqrtf(fmaxf(q1/EE-mu1*mu1,0.f)+EPS);
}

// ds3 = dsi + LN(AY)*sas+sab + LN(AY2)*cas+cab  -> Ds
__device__ __forceinline__ void build_ds3(const float* dsi, const float* accL,
    const float* sasl, const float* sabl, const float* casl, const float* cabl,
    float (*Ds)[1024], float* sm){
  float mu0,rs0,mu1,rs1;
  ln_stats_g(accL+AY, EE, sm, mu0,rs0,mu1,rs1);
  for(int i=threadIdx.x;i<EE;i+=256){ float sc=sasl[i], bi=sabl[i];
    Ds[0][i]=dsi[i]    + (accL[AY+i]-mu0)*rs0*sc + bi;
    Ds[1][i]=dsi[EE+i] + (accL[AY+EE+i]-mu1)*rs1*sc + bi; }
  ln_stats_g(accL+AY2, EE, sm, mu0,rs0,mu1,rs1);
  for(int i=threadIdx.x;i<EE;i+=256){ float sc=casl[i], bi=cabl[i];
    Ds[0][i] += (accL[AY2+i]-mu0)*rs0*sc + bi;
    Ds[1][i] += (accL[AY2+EE+i]-mu1)*rs1*sc + bi; }
}

// ===== prelude: block 0: ds0 = LN(tok[pt]+pos[ti]); blocks 1..39: zero logits +
// layer-0 acc + ds slot 3. grid 40.
__global__ __launch_bounds__(256)
void k_prelude(MegaP p){
  __shared__ float ev[EE];
  __shared__ float sm[16];
  const int t=threadIdx.x, b=blockIdx.x;
  if (b==0){
    int ptv = p.pt[0], tiv = p.ti[0];
    float s0=0,q0=0,d1=0,d2=0;
    for(int i=t;i<EE;i+=256){ float v=p.tok[(size_t)ptv*EE+i]+p.pos[(size_t)tiv*EE+i]; ev[i]=v; s0+=v; q0+=v*v; }
    red4(sm,s0,q0,d1,d2);
    float mu=s0/EE, rs=rsqrtf(fmaxf(q0/EE-mu*mu,0.f)+EPS);
    float* ds0 = p.ws + OFF_DS;
    __syncthreads();
    for(int i=t;i<EE;i+=256){ float y=(ev[i]-mu)*rs*p.ln_s[i]+p.ln_b[i]; ds0[i]=y; ds0[EE+i]=y; }
  } else {
    int idx = (b-1)*256 + t;                   // 9984 zeroing threads
    for (int i=idx; i<2*VV; i+=9984) p.logits[i]=0.f;
    float* a0 = p.ws + OFF_ACC;
    for (int i=idx; i<ACC_STRIDE; i+=9984) a0[i]=0.f;
    float* d3 = p.ws + OFF_DS + 3*2048;
    for (int i=idx; i<2048; i+=9984) d3[i]=0.f;
  }
}

// ===== stage A: x=LN(dsi)+pre_sa_b ; q,k,v = x@{saq,sak,sav}. grid (16,64)
// bx<12: GEMV CH=16 with reg-prefetch; bx>=12: 256 copy blocks for layer-l KV slice
// + zero layer l+1 acc and its glu2 output slot.
__global__ __launch_bounds__(256)
void k_qkv(MegaP p, int l){
  __shared__ float Xs[2][1024];
  __shared__ float sm[16];
  const int t=threadIdx.x, bx=blockIdx.x, by=blockIdx.y;
  if (bx >= 12){
    int cb = (bx-12)*64 + by;                 // [0,256)
    #pragma unroll
    for(int j=0;j<4;j++){
      int idx4 = cb*1024 + j*256 + t;         // 262144 float4 this layer
      int kv = idx4 >> 17;
      int r4 = idx4 & 131071;
      size_t off = (size_t)l*KVL + (size_t)r4*4;
      float4 v = *(const float4*)((kv? p.values_in : p.keys_in) + off);
      *(float4*)((kv? p.values_out : p.keys_out) + off) = v;
    }
    if (l < 11){
      int zi = cb*256 + t;                    // 65536 threads
      float* an = p.ws + OFF_ACC + (size_t)(l+1)*ACC_STRIDE;
      if (zi < ACC_STRIDE) an[zi]=0.f;
      float* dn = p.ws + OFF_DS + (size_t)(3*l+6)*2048;
      if (zi < 2048) dn[zi]=0.f;
    }
    return;
  }
  const float* dsi = p.ws + OFF_DS + (size_t)(3*l)*2048;
  float* accL = p.ws + OFF_ACC + (size_t)l*ACC_STRIDE;
  const size_t lE2=(size_t)l*EE*EE, lE=(size_t)l*EE;
  int c = bx*256 + t;                         // [0,3072)
  int sel = c>>10, cc = c&1023;
  const float* W = (sel==0? p.saq : sel==1? p.sak : p.sav) + lE2;
  float* O = accL + (sel==0? AQ : sel==1? AK : AV);
  int k0 = by*16;
  const float* wp = W + (size_t)k0*EE + cc;
  float wr[16];
  #pragma unroll
  for(int k=0;k<16;k++) wr[k] = wp[(size_t)k*EE];   // issue before prologue
  float mu0,rs0,mu1,rs1;
  ln_stats_g(dsi, EE, sm, mu0,rs0,mu1,rs1);
  for(int i=t;i<EE;i+=256){ float bi=p.pre_sa_b[lE+i];
    Xs[0][i]=(dsi[i]-mu0)*rs0+bi; Xs[1][i]=(dsi[EE+i]-mu1)*rs1+bi; }
  __syncthreads();
  float a0=0,a1=0;
  #pragma unroll
  for(int k=0;k<16;k++){ a0+=Xs[0][k0+k]*wr[k]; a1+=Xs[1][k0+k]*wr[k]; }
  atomicAdd(&O[cc],a0); atomicAdd(&O[EE+cc],a1);
}

// ===== stage C: fused self-attention + y = attn @ sao. grid 256. Writes new KV row.
__global__ __launch_bounds__(256)
void k_selfo(MegaP p, int l){
  __shared__ float Ds[2][1024];
  __shared__ float att[2][256];
  __shared__ float sm[16];
  const int t=threadIdx.x, bkid=blockIdx.x, tiv=p.ti[0];
  float* accL = p.ws + OFF_ACC + (size_t)l*ACC_STRIDE;
  const size_t lE2=(size_t)l*EE*EE;
  int cg=bkid&3, h=(bkid>>2)&15, sub=(bkid>>6)&3, hoff=h*64;
  if (t < 128){ int bb2=t>>6, c2=t&63; Ds[bb2][c2] = accL[AQ + bb2*EE + hoff + c2]*0.125f; }
  __syncthreads();
  for(int bb2=0;bb2<2;bb2++)
    for(int tt=t; tt<=tiv; tt+=256){
      const float* kr = (tt<tiv) ? (p.keys_in + (size_t)l*KVL + (size_t)bb2*KVB + (size_t)tt*EE + hoff)
                                 : (accL + AK + bb2*EE + hoff);
      float d=0;
      #pragma unroll
      for(int c2=0;c2<64;c2++) d += Ds[bb2][c2]*kr[c2];
      att[bb2][tt] = d;
    }
  __syncthreads();
  int wv=t>>6, l2=t&63;
  if (wv<2){
    float m=-3.4e38f;
    for(int tt=l2; tt<=tiv; tt+=64) m=fmaxf(m, att[wv][tt]);
    #pragma unroll
    for(int o=32;o;o>>=1) m=fmaxf(m,__shfl_xor(m,o));
    float s=0;
    for(int tt=l2; tt<=tiv; tt+=64){ float e=__expf(att[wv][tt]-m); att[wv][tt]=e; s+=e; }
    #pragma unroll
    for(int o=32;o;o>>=1) s+=__shfl_xor(s,o);
    if(l2==0) sm[8+wv]=1.f/s;
  }
  __syncthreads();
  {
    int bb2=t>>7, j=(t>>3)&15, part=t&7, colh=sub*16+j;
    float v=0;
    for(int tt=part; tt<=tiv; tt+=8){
      float vv = (tt<tiv)? p.values_in[(size_t)l*KVL + (size_t)bb2*KVB + (size_t)tt*EE + hoff + colh]
                         : accL[AV + bb2*EE + hoff + colh];
      v += att[bb2][tt]*vv;
    }
    v += __shfl_down(v,4,8); v += __shfl_down(v,2,8); v += __shfl_down(v,1,8);
    if(part==0) Ds[bb2][512+j] = v*sm[8+bb2];
  }
  __syncthreads();
  {
    int c = cg*256+t, kb = hoff + sub*16;
    const float* wp = p.sao + lE2 + (size_t)kb*EE + c;
    float a0=0,a1=0;
    #pragma unroll
    for(int j2=0;j2<16;j2++){ float w=wp[(size_t)j2*EE]; a0+=Ds[0][512+j2]*w; a1+=Ds[1][512+j2]*w; }
    atomicAdd(&accL[AY+c],a0); atomicAdd(&accL[AY+EE+c],a1);
  }
  if (cg==0 && sub==0){
    int bb2=t>>7, kv=(t>>6)&1, c2=t&63;
    float val = accL[(kv?AV:AK) + bb2*EE + hoff + c2];
    float* dst = (kv? p.values_out : p.keys_out)
               + (size_t)l*KVL + (size_t)bb2*KVB + (size_t)tiv*EE + hoff + c2;
    *dst = val;
  }
}

// ===== stage D+E1 merged: per-(b,h,ec) block computes ds2->x2 (row b), qc_h, u, partial scores.
// grid (32,4), 256 threads.
__global__ __launch_bounds__(256)
void k_qscore(MegaP p, int l){
  __shared__ float Xs[1024];     // x2 row b
  __shared__ float P[16][64];    // qc partials
  __shared__ float qs[64];
  __shared__ float us[256];
  __shared__ float sm[16];
  const int t=threadIdx.x, bh=blockIdx.x, ec=blockIdx.y;
  const int b=bh>>4, h=bh&15, hoff=h*64;
  float* accL = p.ws + OFF_ACC + (size_t)l*ACC_STRIDE;
  const float* dsi = p.ws + OFF_DS + (size_t)(3*l)*2048;
  const size_t lE2=(size_t)l*EE*EE, lE=(size_t)l*EE;
  const int w=t>>6, ln=t&63;

  // pass 1: LN stats of AY row b
  float s0=0,q0=0;
  for(int i=t;i<EE;i+=256){ float v=accL[AY+b*EE+i]; s0+=v; q0+=v*v; }
  #pragma unroll
  for(int o=32;o;o>>=1){ s0+=__shfl_down(s0,o); q0+=__shfl_down(q0,o); }
  if(ln==0){ sm[w]=s0; sm[4+w]=q0; }
  __syncthreads();
  float mu=(sm[0]+sm[1]+sm[2]+sm[3])/EE;
  float qq=(sm[4]+sm[5]+sm[6]+sm[7])/EE;
  float rs=rsqrtf(fmaxf(qq-mu*mu,0.f)+EPS);
  // pass 2: ds2 row b into Xs + stats
  float s1=0,q1=0;
  for(int i=t;i<EE;i+=256){
    float d = dsi[b*EE+i] + (accL[AY+b*EE+i]-mu)*rs*p.sas[lE+i] + p.sab[lE+i];
    Xs[i]=d; s1+=d; q1+=d*d;
  }
  #pragma unroll
  for(int o=32;o;o>>=1){ s1+=__shfl_down(s1,o); q1+=__shfl_down(q1,o); }
  if(ln==0){ sm[8+w]=s1; sm[12+w]=q1; }
  __syncthreads();
  float mu2=(sm[8]+sm[9]+sm[10]+sm[11])/EE;
  float q2=(sm[12]+sm[13]+sm[14]+sm[15])/EE;
  float rs2=rsqrtf(fmaxf(q2-mu2*mu2,0.f)+EPS);
  for(int i=t;i<EE;i+=256) Xs[i] = (Xs[i]-mu2)*rs2 + p.pre_ca_b[lE+i];
  __syncthreads();

  // qc_h: thread (c4=t&15, kr=t>>4) over rows kr+16i
  {
    int c4=t&15, kr=t>>4;
    const float4* cq = (const float4*)(p.caq + lE2 + (size_t)kr*EE + hoff) + c4;
    float ax=0,ay=0,az=0,aw=0;
    #pragma unroll 8
    for(int i=0;i<64;i++){
      float4 wv = cq[(size_t)i*16*256];      // +16 rows per step (16*EE floats)
      float x = Xs[kr+16*i];
      ax+=x*wv.x; ay+=x*wv.y; az+=x*wv.z; aw+=x*wv.w;
    }
    P[kr][c4*4+0]=ax; P[kr][c4*4+1]=ay; P[kr][c4*4+2]=az; P[kr][c4*4+3]=aw;
  }
  __syncthreads();
  if (t<64){
    float qv=0;
    #pragma unroll
    for(int kr=0;kr<16;kr++) qv += P[kr][t];
    qs[t] = qv*0.125f;
  }
  __syncthreads();

  // u_e for e = ec*256 + t
  {
    const float4* ckp = (const float4*)(p.ckw + lE2 + (size_t)(ec*256+t)*EE + hoff);
    float u=0;
    #pragma unroll
    for(int j=0;j<16;j++){
      float4 wv=ckp[j];
      u += wv.x*qs[4*j] + wv.y*qs[4*j+1] + wv.z*qs[4*j+2] + wv.w*qs[4*j+3];
    }
    us[t]=u;
  }
  __syncthreads();

  // partial scores: s_tt += sum_{e in chunk} u_e * enc[b,tt,e]
  int t2=t&63, q4=t>>6;
  const float4* ep = (const float4*)(p.enc + (size_t)(b*64+t2)*EE + ec*256 + q4*64);
  float pa=0;
  #pragma unroll
  for(int j=0;j<16;j++){
    float4 e4=ep[j];
    pa += e4.x*us[q4*64+4*j] + e4.y*us[q4*64+4*j+1] + e4.z*us[q4*64+4*j+2] + e4.w*us[q4*64+4*j+3];
  }
  atomicAdd(&accL[ASC + (b*16+h)*64 + t2], pa);
}

// ===== stage E2+E3 merged: softmax + ctx slice + partial out + y2 += pout@cao. grid (32,8).
// Exact by linearity: each e-slice's partial out_h is pushed through cao immediately.
__global__ __launch_bounds__(256)
void k_ovy2(MegaP p, int l){
  __shared__ float att[64];
  __shared__ float ctxp[2][128];
  __shared__ float ctxs[128];
  __shared__ float P[256];
  __shared__ float outh[64];
  const int t=threadIdx.x, bh=blockIdx.x, es=blockIdx.y;
  const int b=bh>>4, h=bh&15, hoff=h*64, e0=es*128;
  float* accL = p.ws + OFF_ACC + (size_t)l*ACC_STRIDE;
  const size_t lE2=(size_t)l*EE*EE;
  const int c=t&63, part=t>>6;
  const float* vp = p.cvw + lE2 + (size_t)(e0+part*32)*EE + hoff + c;
  float wr[32];
  #pragma unroll
  for(int j=0;j<32;j++) wr[j] = vp[(size_t)j*EE];     // cvw prefetch
  if (t<64){
    float sc = accL[ASC + (b*16+h)*64 + t];
    int mi=b*64+t;
    bool valid = (p.maski[mi]!=0) || (((const unsigned char*)p.maski)[mi]!=0);
    sc = valid? sc : -3.4e38f;
    float m=sc;
    #pragma unroll
    for(int o=32;o;o>>=1) m=fmaxf(m,__shfl_xor(m,o));
    float e_ = valid? __expf(sc-m) : 0.f;
    float s=e_;
    #pragma unroll
    for(int o=32;o;o>>=1) s+=__shfl_xor(s,o);
    att[t]=e_/s;
  }
  __syncthreads();
  {
    int e2=t>>1, half=t&1;
    const float* ep = p.enc + (size_t)(b*64+half*32)*EE + e0+e2;
    float ca=0;
    #pragma unroll 8
    for(int tt=0;tt<32;tt++) ca += att[half*32+tt]*ep[(size_t)tt*EE];
    ctxp[half][e2]=ca;
  }
  __syncthreads();
  if (t<128) ctxs[t] = ctxp[0][t]+ctxp[1][t];
  __syncthreads();
  {
    float po=0;
    #pragma unroll
    for(int j=0;j<32;j++) po += ctxs[part*32+j]*wr[j];
    P[t]=po;
  }
  __syncthreads();
  if (t<64) outh[t] = P[t]+P[64+t]+P[128+t]+P[192+t];
  __syncthreads();
  // y2[b,n] += sum_c outh[c]*cao[hoff+c, n]  (partial over this e-slice, exact by linearity)
  {
    const float* cop = p.cao + lE2 + (size_t)hoff*EE;
    for(int n=t;n<EE;n+=256){
      float y=0;
      #pragma unroll 8
      for(int c2=0;c2<64;c2++) y += outh[c2]*cop[(size_t)c2*EE + n];
      atomicAdd(&accL[AY2 + b*EE + n], y);
    }
  }
}

// ===== stage G: ds3 ; z=LN(ds3)+g0b ; a=z@f0, b=z@f1. grid (11,64), CH=16, float2
__global__ __launch_bounds__(256)
void k_glu01(MegaP p, int l){
  __shared__ float Xs[2][1024];
  __shared__ float Ds[2][1024];
  __shared__ float sm[16];
  const int t=threadIdx.x;
  const float* dsi = p.ws + OFF_DS + (size_t)(3*l)*2048;
  float* accL = p.ws + OFF_ACC + (size_t)l*ACC_STRIDE;
  const size_t lEG=(size_t)l*EE*GG, lE=(size_t)l*EE;
  int c2 = blockIdx.x*256 + t;
  int k0 = blockIdx.y*16;
  int sel=0, col=0;
  const float* W = nullptr;
  float2 wr[16];
  if (c2 < 2730){
    sel = (c2>=1365); int cc2 = sel? c2-1365 : c2; col = cc2*2;
    W = (sel? p.f1 : p.f0) + lEG;
    const float2* wp = (const float2*)(W + (size_t)k0*GG + col);
    #pragma unroll
    for(int k=0;k<16;k++) wr[k] = wp[(size_t)k*1365];
  }
  build_ds3(dsi, accL, p.sas+lE, p.sab+lE, p.cas+lE, p.cab+lE, Ds, sm);
  float mu0,rs0,mu1,rs1;
  ln_stats_l(Ds, sm, mu0,rs0,mu1,rs1);
  for(int i=t;i<EE;i+=256){ float bi=p.g0b[lE+i];
    Xs[0][i]=(Ds[0][i]-mu0)*rs0+bi; Xs[1][i]=(Ds[1][i]-mu1)*rs1+bi; }
  __syncthreads();
  if (c2 < 2730){
    float* O = accL + (sel? AB2 : AA);
    float a0=0,a1=0,b0=0,b1=0;
    #pragma unroll
    for(int k=0;k<16;k++){
      float x0=Xs[0][k0+k], x1=Xs[1][k0+k];
      a0+=x0*wr[k].x; a1+=x0*wr[k].y; b0+=x1*wr[k].x; b1+=x1*wr[k].y;
    }
    atomicAdd(&O[col+0],a0); atomicAdd(&O[col+1],a1);
    atomicAdd(&O[GG+col+0],b0); atomicAdd(&O[GG+col+1],b1);
  }
}

// ===== stage H: t=gelu(a)*b ; z2=LN(t)+g1b ; ds4 = ds3 + z2@f2. grid (4,86), CH=32
__global__ __launch_bounds__(256)
void k_glu2(MegaP p, int l){
  __shared__ float Xs[2][2736];
  __shared__ float Ds[2][1024];
  __shared__ float sm[16];
  const int t=threadIdx.x;
  const float* dsi = p.ws + OFF_DS + (size_t)(3*l)*2048;
  float* ds4 = p.ws + OFF_DS + (size_t)(3*l+3)*2048;
  float* accL = p.ws + OFF_ACC + (size_t)l*ACC_STRIDE;
  const size_t lGE=(size_t)l*GG*EE, lE=(size_t)l*EE, lG=(size_t)l*GG;
  const int ks = blockIdx.y;
  int c = blockIdx.x*256 + t;
  int k0 = ks*32, k1 = k0+32; if (k1>GG) k1=GG;
  const float* wp = p.f2 + lGE + (size_t)k0*EE + c;
  float wr[32];
  #pragma unroll
  for(int k=0;k<32;k++) wr[k] = (k0+k<GG) ? wp[(size_t)k*EE] : 0.f;
  if (ks==0) build_ds3(dsi, accL, p.sas+lE, p.sab+lE, p.cas+lE, p.cab+lE, Ds, sm);
  float s0=0,q0=0,s1=0,q1=0;
  for(int i=t;i<GG;i+=256){
    float a0v=accL[AA+i], a1v=accL[AA+GG+i];
    float b0v=accL[AB2+i], b1v=accL[AB2+GG+i];
    float g0v=0.5f*a0v*(1.f+erff(a0v*0.70710678118654752f));
    float g1v=0.5f*a1v*(1.f+erff(a1v*0.70710678118654752f));
    float t0=g0v*b0v, t1=g1v*b1v;
    Xs[0][i]=t0; Xs[1][i]=t1;
    s0+=t0;q0+=t0*t0;s1+=t1;q1+=t1*t1;
  }
  red4(sm,s0,q0,s1,q1);
  float mu0=s0/GG, mu1=s1/GG;
  float rs0=rsqrtf(fmaxf(q0/GG-mu0*mu0,0.f)+EPS), rs1=rsqrtf(fmaxf(q1/GG-mu1*mu1,0.f)+EPS);
  for(int i=t;i<GG;i+=256){ float bi=p.g1b[lG+i];
    Xs[0][i]=(Xs[0][i]-mu0)*rs0+bi; Xs[1][i]=(Xs[1][i]-mu1)*rs1+bi; }
  __syncthreads();
  float a0=0,b0=0;
  if (ks==0){ a0=Ds[0][c]; b0=Ds[1][c]; }
  #pragma unroll
  for(int k=0;k<32;k++){
    if (k0+k<GG){ a0+=Xs[0][k0+k]*wr[k]; b0+=Xs[1][k0+k]*wr[k]; }
  }
  atomicAdd(&ds4[c],a0); atomicAdd(&ds4[EE+c],b0);
}

// ===== final: logits = LN(ds,final_b) @ lm_head. grid (17,32), CH=32, float4
__global__ __launch_bounds__(256)
void k_lm(MegaP p){
  __shared__ float Xs[2][1024];
  __shared__ float sm[16];
  const int t=threadIdx.x;
  const float* dsf = p.ws + OFF_DS + (size_t)36*2048;
  float mu0,rs0,mu1,rs1;
  ln_stats_g(dsf, EE, sm, mu0,rs0,mu1,rs1);
  for(int i=t;i<EE;i+=256){ float bi=p.final_b[i];
    Xs[0][i]=(dsf[i]-mu0)*rs0+bi; Xs[1][i]=(dsf[EE+i]-mu1)*rs1+bi; }
  __syncthreads();
  int c4 = blockIdx.x*256 + t;
  if (c4 < 4104){
    int col = c4*4;
    int k0 = blockIdx.y*32;
    const float4* wp = (const float4*)(p.lm_w + (size_t)k0*VV + col);
    float a0=0,a1=0,a2=0,a3=0,b0=0,b1=0,b2=0,b3=0;
    #pragma unroll 8
    for(int k=0;k<32;k++){
      float4 w=*wp; wp+=4104;
      float x0=Xs[0][k0+k], x1=Xs[1][k0+k];
      a0+=x0*w.x; a1+=x0*w.y; a2+=x0*w.z; a3+=x0*w.w;
      b0+=x1*w.x; b1+=x1*w.y; b2+=x1*w.z; b3+=x1*w.w;
    }
    atomicAdd(&p.logits[col+0],a0); atomicAdd(&p.logits[col+1],a1);
    atomicAdd(&p.logits[col+2],a2); atomicAdd(&p.logits[col+3],a3);
    atomicAdd(&p.logits[VV+col+0],b0); atomicAdd(&p.logits[VV+col+1],b1);
    atomicAdd(&p.logits[VV+col+2],b2); atomicAdd(&p.logits[VV+col+3],b3);
  }
}

extern "C" void kernel_launch(void* const* d_in, const int* in_sizes, int n_in,
                              void* d_out, int out_size, void* d_ws, size_t ws_size,
                              hipStream_t stream){
  (void)in_sizes; (void)n_in; (void)out_size; (void)ws_size;
  float* out = (float*)d_out;
  float* ws = (float*)d_ws;

  MegaP P;
  P.enc        = (const float*)d_in[0];
  P.keys_in    = (const float*)d_in[1];
  P.values_in  = (const float*)d_in[2];
  P.maski      = (const int*)d_in[3];
  P.pt         = (const int*)d_in[4];
  P.ti         = (const int*)d_in[5];
  P.tok        = (const float*)d_in[6];
  P.pos        = (const float*)d_in[7];
  P.ln_s       = (const float*)d_in[8];
  P.ln_b       = (const float*)d_in[9];
  P.final_b    = (const float*)d_in[10];
  P.lm_w       = (const float*)d_in[11];
  P.pre_sa_b   = (const float*)d_in[12];
  P.saq        = (const float*)d_in[13];
  P.sak        = (const float*)d_in[14];
  P.sav        = (const float*)d_in[15];
  P.sao        = (const float*)d_in[16];
  P.sas        = (const float*)d_in[17];
  P.sab        = (const float*)d_in[18];
  P.pre_ca_b   = (const float*)d_in[19];
  P.caq        = (const float*)d_in[20];
  P.ckw        = (const float*)d_in[21];
  P.cvw        = (const float*)d_in[22];
  P.cao        = (const float*)d_in[23];
  P.cas        = (const float*)d_in[24];
  P.cab        = (const float*)d_in[25];
  P.g0b        = (const float*)d_in[26];
  P.f0         = (const float*)d_in[27];
  P.f1         = (const float*)d_in[28];
  P.g1b        = (const float*)d_in[29];
  P.f2         = (const float*)d_in[30];
  P.logits     = out;
  P.keys_out   = out + (size_t)2*VV;
  P.values_out = P.keys_out + (size_t)LAYERS*KVL;
  P.ws         = ws;

  k_prelude<<<40,256,0,stream>>>(P);
  for (int l=0;l<LAYERS;l++){
    k_qkv   <<<dim3(16,64),256,0,stream>>>(P,l);
    k_selfo <<<256,        256,0,stream>>>(P,l);
    k_qscore<<<dim3(32,4), 256,0,stream>>>(P,l);
    k_ovy2  <<<dim3(32,8), 256,0,stream>>>(P,l);
    k_glu01 <<<dim3(11,64),256,0,stream>>>(P,l);
    k_glu2  <<<dim3(4,86), 256,0,stream>>>(P,l);
  }
  k_lm<<<dim3(17,32),256,0,stream>>>(P);
}

// Round 13
// 1060.619 us; speedup vs baseline: 1.5372x; 1.1664x over previous
//
#include <hip/hip_runtime.h>
#include <math.h>

#define LAYERS 12
#define EE 1024
#define GG 2730
#define VV 16416
#define EPS 1e-6f

// ---- workspace layout (float offsets) ----
#define OFF_DS 0
#define NSLOT 37
#define OFF_ACC (OFF_DS + NSLOT*2048)
#define ACC_STRIDE 28672
#define AQ 0
#define AK 2048
#define AV 4096
#define AY 6144
#define ASC 10240
#define AOUT 12288
#define AY2 14336
#define AA 16384
#define AB2 21844
#define ACC_TOTAL (LAYERS*ACC_STRIDE)

#define KVL 524288   // floats per layer per cache (2 batches x 256 x 1024)
#define KVB 262144   // floats per batch

struct MegaP {
  const float* enc; const float* keys_in; const float* values_in;
  const int* maski; const int* pt; const int* ti;
  const float* tok; const float* pos; const float* ln_s; const float* ln_b;
  const float* final_b; const float* lm_w;
  const float* pre_sa_b; const float* saq; const float* sak; const float* sav;
  const float* sao; const float* sas; const float* sab;
  const float* pre_ca_b; const float* caq; const float* ckw; const float* cvw;
  const float* cao; const float* cas; const float* cab;
  const float* g0b; const float* f0; const float* f1; const float* g1b; const float* f2;
  float* logits; float* keys_out; float* values_out; float* ws;
};

__device__ __forceinline__ void red4(float* sm, float& a, float& b, float& c, float& d){
  #pragma unroll
  for(int o=32;o;o>>=1){ a+=__shfl_down(a,o); b+=__shfl_down(b,o); c+=__shfl_down(c,o); d+=__shfl_down(d,o); }
  int w=threadIdx.x>>6, l=threadIdx.x&63;
  __syncthreads();
  if(l==0){ sm[w]=a; sm[4+w]=b; sm[8+w]=c; sm[12+w]=d; }
  __syncthreads();
  a=sm[0]+sm[1]+sm[2]+sm[3]; b=sm[4]+sm[5]+sm[6]+sm[7];
  c=sm[8]+sm[9]+sm[10]+sm[11]; d=sm[12]+sm[13]+sm[14]+sm[15];
}

__device__ __forceinline__ void ln_stats_g(const float* v, int K, float* sm,
    float& mu0, float& rs0, float& mu1, float& rs1){
  float s0=0,q0=0,s1=0,q1=0;
  for(int i=threadIdx.x;i<K;i+=256){ float a=v[i], b=v[K+i]; s0+=a;q0+=a*a;s1+=b;q1+=b*b; }
  red4(sm,s0,q0,s1,q1);
  mu0=s0/K; mu1=s1/K;
  rs0=rsqrtf(fmaxf(q0/K-mu0*mu0,0.f)+EPS);
  rs1=rsqrtf(fmaxf(q1/K-mu1*mu1,0.f)+EPS);
}

__device__ __forceinline__ void ln_stats_l(float (*Ds)[1024], float* sm,
    float& mu0, float& rs0, float& mu1, float& rs1){
  float s0=0,q0=0,s1=0,q1=0;
  for(int i=threadIdx.x;i<EE;i+=256){ float a=Ds[0][i], b=Ds[1][i]; s0+=a;q0+=a*a;s1+=b;q1+=b*b; }
  red4(sm,s0,q0,s1,q1);
  mu0=s0/EE; mu1=s1/EE;
  rs0=rsqrtf(fmaxf(q0/EE-mu0*mu0,0.f)+EPS);
  rs1=rsqrtf(fmaxf(q1/EE-mu1*mu1,0.f)+EPS);
}

// ds3 = dsi + LN(AY)*sas+sab + LN(AY2)*cas+cab  -> Ds
__device__ __forceinline__ void build_ds3(const float* dsi, const float* accL,
    const float* sasl, const float* sabl, const float* casl, const float* cabl,
    float (*Ds)[1024], float* sm){
  float mu0,rs0,mu1,rs1;
  ln_stats_g(accL+AY, EE, sm, mu0,rs0,mu1,rs1);
  for(int i=threadIdx.x;i<EE;i+=256){ float sc=sasl[i], bi=sabl[i];
    Ds[0][i]=dsi[i]    + (accL[AY+i]-mu0)*rs0*sc + bi;
    Ds[1][i]=dsi[EE+i] + (accL[AY+EE+i]-mu1)*rs1*sc + bi; }
  ln_stats_g(accL+AY2, EE, sm, mu0,rs0,mu1,rs1);
  for(int i=threadIdx.x;i<EE;i+=256){ float sc=casl[i], bi=cabl[i];
    Ds[0][i] += (accL[AY2+i]-mu0)*rs0*sc + bi;
    Ds[1][i] += (accL[AY2+EE+i]-mu1)*rs1*sc + bi; }
}

// ===== prelude: block 0: ds0 = LN(tok[pt]+pos[ti]); blocks 1..39: zero logits +
// layer-0 acc + layer-0 ds4 slot. grid 40.
__global__ __launch_bounds__(256)
void k_prelude(MegaP p){
  __shared__ float ev[EE];
  __shared__ float sm[16];
  const int t=threadIdx.x, b=blockIdx.x;
  if (b==0){
    int ptv = p.pt[0], tiv = p.ti[0];
    float s0=0,q0=0,d1=0,d2=0;
    for(int i=t;i<EE;i+=256){ float v=p.tok[(size_t)ptv*EE+i]+p.pos[(size_t)tiv*EE+i]; ev[i]=v; s0+=v; q0+=v*v; }
    red4(sm,s0,q0,d1,d2);
    float mu=s0/EE, rs=rsqrtf(fmaxf(q0/EE-mu*mu,0.f)+EPS);
    float* ds0 = p.ws + OFF_DS;
    __syncthreads();
    for(int i=t;i<EE;i+=256){ float y=(ev[i]-mu)*rs*p.ln_s[i]+p.ln_b[i]; ds0[i]=y; ds0[EE+i]=y; }
  } else {
    int idx = (b-1)*256 + t;                   // 9984 zeroing threads
    for (int i=idx; i<2*VV; i+=9984) p.logits[i]=0.f;
    float* a0 = p.ws + OFF_ACC;
    for (int i=idx; i<ACC_STRIDE; i+=9984) a0[i]=0.f;
    float* d3 = p.ws + OFF_DS + 3*2048;
    for (int i=idx; i<2048; i+=9984) d3[i]=0.f;
  }
}

// ===== stage A: x=LN(dsi)+pre_sa_b ; q,k,v = x@{saq,sak,sav}. grid (16,64)
// bx<12: GEMV CH=16 with reg-prefetch; bx>=12: 256 copy blocks for layer-l KV slice
// + zero layer l+1 acc and its ds4 slot.
__global__ __launch_bounds__(256)
void k_qkv(MegaP p, int l){
  __shared__ float Xs[2][1024];
  __shared__ float sm[16];
  const int t=threadIdx.x, bx=blockIdx.x, by=blockIdx.y;
  if (bx >= 12){
    int cb = (bx-12)*64 + by;                 // [0,256)
    #pragma unroll
    for(int j=0;j<4;j++){
      int idx4 = cb*1024 + j*256 + t;         // 262144 float4 this layer
      int kv = idx4 >> 17;
      int r4 = idx4 & 131071;
      size_t off = (size_t)l*KVL + (size_t)r4*4;
      float4 v = *(const float4*)((kv? p.values_in : p.keys_in) + off);
      *(float4*)((kv? p.values_out : p.keys_out) + off) = v;
    }
    if (l < 11){
      int zi = cb*256 + t;                    // 65536 threads
      float* an = p.ws + OFF_ACC + (size_t)(l+1)*ACC_STRIDE;
      if (zi < ACC_STRIDE) an[zi]=0.f;
      float* dn = p.ws + OFF_DS + (size_t)(3*l+6)*2048;
      if (zi < 2048) dn[zi]=0.f;
    }
    return;
  }
  const float* dsi = p.ws + OFF_DS + (size_t)(3*l)*2048;
  float* accL = p.ws + OFF_ACC + (size_t)l*ACC_STRIDE;
  const size_t lE2=(size_t)l*EE*EE, lE=(size_t)l*EE;
  int c = bx*256 + t;                         // [0,3072)
  int sel = c>>10, cc = c&1023;
  const float* W = (sel==0? p.saq : sel==1? p.sak : p.sav) + lE2;
  float* O = accL + (sel==0? AQ : sel==1? AK : AV);
  int k0 = by*16;
  const float* wp = W + (size_t)k0*EE + cc;
  float wr[16];
  #pragma unroll
  for(int k=0;k<16;k++) wr[k] = wp[(size_t)k*EE];   // issue before prologue
  float mu0,rs0,mu1,rs1;
  ln_stats_g(dsi, EE, sm, mu0,rs0,mu1,rs1);
  for(int i=t;i<EE;i+=256){ float bi=p.pre_sa_b[lE+i];
    Xs[0][i]=(dsi[i]-mu0)*rs0+bi; Xs[1][i]=(dsi[EE+i]-mu1)*rs1+bi; }
  __syncthreads();
  float a0=0,a1=0;
  #pragma unroll
  for(int k=0;k<16;k++){ a0+=Xs[0][k0+k]*wr[k]; a1+=Xs[1][k0+k]*wr[k]; }
  atomicAdd(&O[cc],a0); atomicAdd(&O[EE+cc],a1);
}

// ===== stage C: fused self-attention + y = attn @ sao. grid 256. Writes new KV row.
__global__ __launch_bounds__(256)
void k_selfo(MegaP p, int l){
  __shared__ float Ds[2][1024];
  __shared__ float att[2][256];
  __shared__ float sm[16];
  const int t=threadIdx.x, bkid=blockIdx.x, tiv=p.ti[0];
  float* accL = p.ws + OFF_ACC + (size_t)l*ACC_STRIDE;
  const size_t lE2=(size_t)l*EE*EE;
  int cg=bkid&3, h=(bkid>>2)&15, sub=(bkid>>6)&3, hoff=h*64;
  if (t < 128){ int bb2=t>>6, c2=t&63; Ds[bb2][c2] = accL[AQ + bb2*EE + hoff + c2]*0.125f; }
  __syncthreads();
  for(int bb2=0;bb2<2;bb2++)
    for(int tt=t; tt<=tiv; tt+=256){
      const float* kr = (tt<tiv) ? (p.keys_in + (size_t)l*KVL + (size_t)bb2*KVB + (size_t)tt*EE + hoff)
                                 : (accL + AK + bb2*EE + hoff);
      float d=0;
      #pragma unroll
      for(int c2=0;c2<64;c2++) d += Ds[bb2][c2]*kr[c2];
      att[bb2][tt] = d;
    }
  __syncthreads();
  int wv=t>>6, l2=t&63;
  if (wv<2){
    float m=-3.4e38f;
    for(int tt=l2; tt<=tiv; tt+=64) m=fmaxf(m, att[wv][tt]);
    #pragma unroll
    for(int o=32;o;o>>=1) m=fmaxf(m,__shfl_xor(m,o));
    float s=0;
    for(int tt=l2; tt<=tiv; tt+=64){ float e=__expf(att[wv][tt]-m); att[wv][tt]=e; s+=e; }
    #pragma unroll
    for(int o=32;o;o>>=1) s+=__shfl_xor(s,o);
    if(l2==0) sm[8+wv]=1.f/s;
  }
  __syncthreads();
  {
    int bb2=t>>7, j=(t>>3)&15, part=t&7, colh=sub*16+j;
    float v=0;
    for(int tt=part; tt<=tiv; tt+=8){
      float vv = (tt<tiv)? p.values_in[(size_t)l*KVL + (size_t)bb2*KVB + (size_t)tt*EE + hoff + colh]
                         : accL[AV + bb2*EE + hoff + colh];
      v += att[bb2][tt]*vv;
    }
    v += __shfl_down(v,4,8); v += __shfl_down(v,2,8); v += __shfl_down(v,1,8);
    if(part==0) Ds[bb2][512+j] = v*sm[8+bb2];
  }
  __syncthreads();
  {
    int c = cg*256+t, kb = hoff + sub*16;
    const float* wp = p.sao + lE2 + (size_t)kb*EE + c;
    float a0=0,a1=0;
    #pragma unroll
    for(int j2=0;j2<16;j2++){ float w=wp[(size_t)j2*EE]; a0+=Ds[0][512+j2]*w; a1+=Ds[1][512+j2]*w; }
    atomicAdd(&accL[AY+c],a0); atomicAdd(&accL[AY+EE+c],a1);
  }
  if (cg==0 && sub==0){
    int bb2=t>>7, kv=(t>>6)&1, c2=t&63;
    float val = accL[(kv?AV:AK) + bb2*EE + hoff + c2];
    float* dst = (kv? p.values_out : p.keys_out)
               + (size_t)l*KVL + (size_t)bb2*KVB + (size_t)tiv*EE + hoff + c2;
    *dst = val;
  }
}

// ===== stage D+E1 merged: per-(b,h,ec) block computes ds2->x2 (row b), qc_h, u, partial scores.
// grid (32,4), 256 threads.
__global__ __launch_bounds__(256)
void k_qscore(MegaP p, int l){
  __shared__ float Xs[1024];     // x2 row b
  __shared__ float P[16][64];    // qc partials
  __shared__ float qs[64];
  __shared__ float us[256];
  __shared__ float sm[16];
  const int t=threadIdx.x, bh=blockIdx.x, ec=blockIdx.y;
  const int b=bh>>4, h=bh&15, hoff=h*64;
  float* accL = p.ws + OFF_ACC + (size_t)l*ACC_STRIDE;
  const float* dsi = p.ws + OFF_DS + (size_t)(3*l)*2048;
  const size_t lE2=(size_t)l*EE*EE, lE=(size_t)l*EE;
  const int w=t>>6, ln=t&63;

  // pass 1: LN stats of AY row b
  float s0=0,q0=0;
  for(int i=t;i<EE;i+=256){ float v=accL[AY+b*EE+i]; s0+=v; q0+=v*v; }
  #pragma unroll
  for(int o=32;o;o>>=1){ s0+=__shfl_down(s0,o); q0+=__shfl_down(q0,o); }
  if(ln==0){ sm[w]=s0; sm[4+w]=q0; }
  __syncthreads();
  float mu=(sm[0]+sm[1]+sm[2]+sm[3])/EE;
  float qq=(sm[4]+sm[5]+sm[6]+sm[7])/EE;
  float rs=rsqrtf(fmaxf(qq-mu*mu,0.f)+EPS);
  // pass 2: ds2 row b into Xs + stats
  float s1=0,q1=0;
  for(int i=t;i<EE;i+=256){
    float d = dsi[b*EE+i] + (accL[AY+b*EE+i]-mu)*rs*p.sas[lE+i] + p.sab[lE+i];
    Xs[i]=d; s1+=d; q1+=d*d;
  }
  #pragma unroll
  for(int o=32;o;o>>=1){ s1+=__shfl_down(s1,o); q1+=__shfl_down(q1,o); }
  if(ln==0){ sm[8+w]=s1; sm[12+w]=q1; }
  __syncthreads();
  float mu2=(sm[8]+sm[9]+sm[10]+sm[11])/EE;
  float q2=(sm[12]+sm[13]+sm[14]+sm[15])/EE;
  float rs2=rsqrtf(fmaxf(q2-mu2*mu2,0.f)+EPS);
  for(int i=t;i<EE;i+=256) Xs[i] = (Xs[i]-mu2)*rs2 + p.pre_ca_b[lE+i];
  __syncthreads();

  // qc_h: thread (c4=t&15, kr=t>>4) over rows kr+16i
  {
    int c4=t&15, kr=t>>4;
    const float4* cq = (const float4*)(p.caq + lE2 + (size_t)kr*EE + hoff) + c4;
    float ax=0,ay=0,az=0,aw=0;
    #pragma unroll 8
    for(int i=0;i<64;i++){
      float4 wv = cq[(size_t)i*16*256];      // +16 rows per step (16*EE floats)
      float x = Xs[kr+16*i];
      ax+=x*wv.x; ay+=x*wv.y; az+=x*wv.z; aw+=x*wv.w;
    }
    P[kr][c4*4+0]=ax; P[kr][c4*4+1]=ay; P[kr][c4*4+2]=az; P[kr][c4*4+3]=aw;
  }
  __syncthreads();
  if (t<64){
    float qv=0;
    #pragma unroll
    for(int kr=0;kr<16;kr++) qv += P[kr][t];
    qs[t] = qv*0.125f;
  }
  __syncthreads();

  // u_e for e = ec*256 + t
  {
    const float4* ckp = (const float4*)(p.ckw + lE2 + (size_t)(ec*256+t)*EE + hoff);
    float u=0;
    #pragma unroll
    for(int j=0;j<16;j++){
      float4 wv=ckp[j];
      u += wv.x*qs[4*j] + wv.y*qs[4*j+1] + wv.z*qs[4*j+2] + wv.w*qs[4*j+3];
    }
    us[t]=u;
  }
  __syncthreads();

  // partial scores: s_tt += sum_{e in chunk} u_e * enc[b,tt,e]
  int t2=t&63, q4=t>>6;
  const float4* ep = (const float4*)(p.enc + (size_t)(b*64+t2)*EE + ec*256 + q4*64);
  float pa=0;
  #pragma unroll
  for(int j=0;j<16;j++){
    float4 e4=ep[j];
    pa += e4.x*us[q4*64+4*j] + e4.y*us[q4*64+4*j+1] + e4.z*us[q4*64+4*j+2] + e4.w*us[q4*64+4*j+3];
  }
  atomicAdd(&accL[ASC + (b*16+h)*64 + t2], pa);
}

// ===== stage E2: softmax + ctx + out = ctx@cvw. grid (32,8): (b,h) x e-range 128.
__global__ __launch_bounds__(256)
void k_ov(MegaP p, int l){
  __shared__ float att[64];
  __shared__ float ctxp[2][128];
  __shared__ float ctxs[128];
  __shared__ float smr[2];
  const int t=threadIdx.x, bh=blockIdx.x, es=blockIdx.y;
  const int b=bh>>4, h=bh&15, hoff=h*64, e0=es*128;
  float* accL = p.ws + OFF_ACC + (size_t)l*ACC_STRIDE;
  const size_t lE2=(size_t)l*EE*EE;
  const int c=t&63, part=t>>6;
  const float* vp = p.cvw + lE2 + (size_t)(e0+part*32)*EE + hoff + c;
  float wr[32];
  #pragma unroll
  for(int j=0;j<32;j++) wr[j] = vp[(size_t)j*EE];     // cvw prefetch
  if (t<64){
    float sc = accL[ASC + (b*16+h)*64 + t];
    int mi=b*64+t;
    bool valid = (p.maski[mi]!=0) || (((const unsigned char*)p.maski)[mi]!=0);
    sc = valid? sc : -3.4e38f;
    float m=sc;
    #pragma unroll
    for(int o=32;o;o>>=1) m=fmaxf(m,__shfl_xor(m,o));
    float e_ = valid? __expf(sc-m) : 0.f;
    float s=e_;
    #pragma unroll
    for(int o=32;o;o>>=1) s+=__shfl_xor(s,o);
    att[t]=e_;
    if(t==0) smr[0]=1.f/s;
  }
  __syncthreads();
  {
    int e2=t>>1, half=t&1;
    const float* ep = p.enc + (size_t)(b*64+half*32)*EE + e0+e2;
    float ca=0;
    #pragma unroll 8
    for(int tt=0;tt<32;tt++) ca += att[half*32+tt]*ep[(size_t)tt*EE];
    ctxp[half][e2]=ca;
  }
  __syncthreads();
  if (t<128) ctxs[t] = (ctxp[0][t]+ctxp[1][t])*smr[0];
  __syncthreads();
  float a=0;
  #pragma unroll
  for(int j=0;j<32;j++) a += ctxs[part*32+j]*wr[j];
  atomicAdd(&accL[AOUT + b*EE + hoff + c], a);
}

// ===== stage E3: y2 = out @ cao. grid (4,64), CH=16
__global__ __launch_bounds__(256)
void k_y2(MegaP p, int l){
  __shared__ float Xs[2][1024];
  const int t=threadIdx.x;
  float* accL = p.ws + OFF_ACC + (size_t)l*ACC_STRIDE;
  const size_t lE2=(size_t)l*EE*EE;
  int c = blockIdx.x*256 + t;
  int k0 = blockIdx.y*16;
  const float* wp = p.cao + lE2 + (size_t)k0*EE + c;
  float wr[16];
  #pragma unroll
  for(int k=0;k<16;k++) wr[k] = wp[(size_t)k*EE];
  for(int i=t;i<EE;i+=256){ Xs[0][i]=accL[AOUT+i]; Xs[1][i]=accL[AOUT+EE+i]; }
  __syncthreads();
  float a0=0,a1=0;
  #pragma unroll
  for(int k=0;k<16;k++){ a0+=Xs[0][k0+k]*wr[k]; a1+=Xs[1][k0+k]*wr[k]; }
  atomicAdd(&accL[AY2+c],a0); atomicAdd(&accL[AY2+EE+c],a1);
}

// ===== stage G: ds3 ; z=LN(ds3)+g0b ; a=z@f0, b=z@f1. grid (11,64), CH=16, float2
__global__ __launch_bounds__(256)
void k_glu01(MegaP p, int l){
  __shared__ float Xs[2][1024];
  __shared__ float Ds[2][1024];
  __shared__ float sm[16];
  const int t=threadIdx.x;
  const float* dsi = p.ws + OFF_DS + (size_t)(3*l)*2048;
  float* accL = p.ws + OFF_ACC + (size_t)l*ACC_STRIDE;
  const size_t lEG=(size_t)l*EE*GG, lE=(size_t)l*EE;
  int c2 = blockIdx.x*256 + t;
  int k0 = blockIdx.y*16;
  int sel=0, col=0;
  const float* W = nullptr;
  float2 wr[16];
  if (c2 < 2730){
    sel = (c2>=1365); int cc2 = sel? c2-1365 : c2; col = cc2*2;
    W = (sel? p.f1 : p.f0) + lEG;
    const float2* wp = (const float2*)(W + (size_t)k0*GG + col);
    #pragma unroll
    for(int k=0;k<16;k++) wr[k] = wp[(size_t)k*1365];
  }
  build_ds3(dsi, accL, p.sas+lE, p.sab+lE, p.cas+lE, p.cab+lE, Ds, sm);
  float mu0,rs0,mu1,rs1;
  ln_stats_l(Ds, sm, mu0,rs0,mu1,rs1);
  for(int i=t;i<EE;i+=256){ float bi=p.g0b[lE+i];
    Xs[0][i]=(Ds[0][i]-mu0)*rs0+bi; Xs[1][i]=(Ds[1][i]-mu1)*rs1+bi; }
  __syncthreads();
  if (c2 < 2730){
    float* O = accL + (sel? AB2 : AA);
    float a0=0,a1=0,b0=0,b1=0;
    #pragma unroll
    for(int k=0;k<16;k++){
      float x0=Xs[0][k0+k], x1=Xs[1][k0+k];
      a0+=x0*wr[k].x; a1+=x0*wr[k].y; b0+=x1*wr[k].x; b1+=x1*wr[k].y;
    }
    atomicAdd(&O[col+0],a0); atomicAdd(&O[col+1],a1);
    atomicAdd(&O[GG+col+0],b0); atomicAdd(&O[GG+col+1],b1);
  }
}

// ===== stage H: t=gelu(a)*b ; z2=LN(t)+g1b ; ds4 = ds3 + z2@f2. grid (4,86), CH=32
__global__ __launch_bounds__(256)
void k_glu2(MegaP p, int l){
  __shared__ float Xs[2][2736];
  __shared__ float Ds[2][1024];
  __shared__ float sm[16];
  const int t=threadIdx.x;
  const float* dsi = p.ws + OFF_DS + (size_t)(3*l)*2048;
  float* ds4 = p.ws + OFF_DS + (size_t)(3*l+3)*2048;
  float* accL = p.ws + OFF_ACC + (size_t)l*ACC_STRIDE;
  const size_t lGE=(size_t)l*GG*EE, lE=(size_t)l*EE, lG=(size_t)l*GG;
  const int ks = blockIdx.y;
  int c = blockIdx.x*256 + t;
  int k0 = ks*32, k1 = k0+32; if (k1>GG) k1=GG;
  const float* wp = p.f2 + lGE + (size_t)k0*EE + c;
  float wr[32];
  #pragma unroll
  for(int k=0;k<32;k++) wr[k] = (k0+k<GG) ? wp[(size_t)k*EE] : 0.f;
  if (ks==0) build_ds3(dsi, accL, p.sas+lE, p.sab+lE, p.cas+lE, p.cab+lE, Ds, sm);
  float s0=0,q0=0,s1=0,q1=0;
  for(int i=t;i<GG;i+=256){
    float a0v=accL[AA+i], a1v=accL[AA+GG+i];
    float b0v=accL[AB2+i], b1v=accL[AB2+GG+i];
    float g0v=0.5f*a0v*(1.f+erff(a0v*0.70710678118654752f));
    float g1v=0.5f*a1v*(1.f+erff(a1v*0.70710678118654752f));
    float t0=g0v*b0v, t1=g1v*b1v;
    Xs[0][i]=t0; Xs[1][i]=t1;
    s0+=t0;q0+=t0*t0;s1+=t1;q1+=t1*t1;
  }
  red4(sm,s0,q0,s1,q1);
  float mu0=s0/GG, mu1=s1/GG;
  float rs0=rsqrtf(fmaxf(q0/GG-mu0*mu0,0.f)+EPS), rs1=rsqrtf(fmaxf(q1/GG-mu1*mu1,0.f)+EPS);
  for(int i=t;i<GG;i+=256){ float bi=p.g1b[lG+i];
    Xs[0][i]=(Xs[0][i]-mu0)*rs0+bi; Xs[1][i]=(Xs[1][i]-mu1)*rs1+bi; }
  __syncthreads();
  float a0=0,b0=0;
  if (ks==0){ a0=Ds[0][c]; b0=Ds[1][c]; }
  #pragma unroll
  for(int k=0;k<32;k++){
    if (k0+k<GG){ a0+=Xs[0][k0+k]*wr[k]; b0+=Xs[1][k0+k]*wr[k]; }
  }
  atomicAdd(&ds4[c],a0); atomicAdd(&ds4[EE+c],b0);
}

// ===== final: logits = LN(ds,final_b) @ lm_head. grid (17,32), CH=32, float4
__global__ __launch_bounds__(256)
void k_lm(MegaP p){
  __shared__ float Xs[2][1024];
  __shared__ float sm[16];
  const int t=threadIdx.x;
  const float* dsf = p.ws + OFF_DS + (size_t)36*2048;
  float mu0,rs0,mu1,rs1;
  ln_stats_g(dsf, EE, sm, mu0,rs0,mu1,rs1);
  for(int i=t;i<EE;i+=256){ float bi=p.final_b[i];
    Xs[0][i]=(dsf[i]-mu0)*rs0+bi; Xs[1][i]=(dsf[EE+i]-mu1)*rs1+bi; }
  __syncthreads();
  int c4 = blockIdx.x*256 + t;
  if (c4 < 4104){
    int col = c4*4;
    int k0 = blockIdx.y*32;
    const float4* wp = (const float4*)(p.lm_w + (size_t)k0*VV + col);
    float a0=0,a1=0,a2=0,a3=0,b0=0,b1=0,b2=0,b3=0;
    #pragma unroll 8
    for(int k=0;k<32;k++){
      float4 w=*wp; wp+=4104;
      float x0=Xs[0][k0+k], x1=Xs[1][k0+k];
      a0+=x0*w.x; a1+=x0*w.y; a2+=x0*w.z; a3+=x0*w.w;
      b0+=x1*w.x; b1+=x1*w.y; b2+=x1*w.z; b3+=x1*w.w;
    }
    atomicAdd(&p.logits[col+0],a0); atomicAdd(&p.logits[col+1],a1);
    atomicAdd(&p.logits[col+2],a2); atomicAdd(&p.logits[col+3],a3);
    atomicAdd(&p.logits[VV+col+0],b0); atomicAdd(&p.logits[VV+col+1],b1);
    atomicAdd(&p.logits[VV+col+2],b2); atomicAdd(&p.logits[VV+col+3],b3);
  }
}

extern "C" void kernel_launch(void* const* d_in, const int* in_sizes, int n_in,
                              void* d_out, int out_size, void* d_ws, size_t ws_size,
                              hipStream_t stream){
  (void)in_sizes; (void)n_in; (void)out_size; (void)ws_size;
  float* out = (float*)d_out;
  float* ws = (float*)d_ws;

  MegaP P;
  P.enc        = (const float*)d_in[0];
  P.keys_in    = (const float*)d_in[1];
  P.values_in  = (const float*)d_in[2];
  P.maski      = (const int*)d_in[3];
  P.pt         = (const int*)d_in[4];
  P.ti         = (const int*)d_in[5];
  P.tok        = (const float*)d_in[6];
  P.pos        = (const float*)d_in[7];
  P.ln_s       = (const float*)d_in[8];
  P.ln_b       = (const float*)d_in[9];
  P.final_b    = (const float*)d_in[10];
  P.lm_w       = (const float*)d_in[11];
  P.pre_sa_b   = (const float*)d_in[12];
  P.saq        = (const float*)d_in[13];
  P.sak        = (const float*)d_in[14];
  P.sav        = (const float*)d_in[15];
  P.sao        = (const float*)d_in[16];
  P.sas        = (const float*)d_in[17];
  P.sab        = (const float*)d_in[18];
  P.pre_ca_b   = (const float*)d_in[19];
  P.caq        = (const float*)d_in[20];
  P.ckw        = (const float*)d_in[21];
  P.cvw        = (const float*)d_in[22];
  P.cao        = (const float*)d_in[23];
  P.cas        = (const float*)d_in[24];
  P.cab        = (const float*)d_in[25];
  P.g0b        = (const float*)d_in[26];
  P.f0         = (const float*)d_in[27];
  P.f1         = (const float*)d_in[28];
  P.g1b        = (const float*)d_in[29];
  P.f2         = (const float*)d_in[30];
  P.logits     = out;
  P.keys_out   = out + (size_t)2*VV;
  P.values_out = P.keys_out + (size_t)LAYERS*KVL;
  P.ws         = ws;

  k_prelude<<<40,256,0,stream>>>(P);
  for (int l=0;l<LAYERS;l++){
    k_qkv   <<<dim3(16,64),256,0,stream>>>(P,l);
    k_selfo <<<256,        256,0,stream>>>(P,l);
    k_qscore<<<dim3(32,4), 256,0,stream>>>(P,l);
    k_ov    <<<dim3(32,8), 256,0,stream>>>(P,l);
    k_y2    <<<dim3(4,64), 256,0,stream>>>(P,l);
    k_glu01 <<<dim3(11,64),256,0,stream>>>(P,l);
    k_glu2  <<<dim3(4,86), 256,0,stream>>>(P,l);
  }
  k_lm<<<dim3(17,32),256,0,stream>>>(P);
}